// Round 10
// baseline (186.660 us; speedup 1.0000x reference)
//
#include <hip/hip_runtime.h>
#include <hip/hip_bf16.h>

namespace {
constexpr int NODES = 100000;
constexpr int EMBD  = 128;
constexpr int BATCH = 1024;
constexpr int NPASS = 8;      // 1024 rows / (4 waves * 32 rows)
constexpr int NBLK  = 512;    // exactly 2 blocks/CU, zero residency imbalance
constexpr int NWIDE = 106;    // 106 strips of 208 cols + 406 of 192 = 100000
}

typedef __attribute__((ext_vector_type(8))) short bf16x8_t;
typedef __attribute__((ext_vector_type(4))) float f32x4_t;

__device__ __forceinline__ short f2bf(float f) {
    __hip_bfloat16 h = __float2bfloat16(f);
    short s; __builtin_memcpy(&s, &h, 2); return s;
}

__device__ __forceinline__ int strip_start(int bid) {
    return 192 * bid + 16 * ((bid * NWIDE) >> 9);   // /512
}

// combined[b][k] = emb[subj[b]][k] * rels[rel[b]][k], bf16 (A matrix, 256 KB)
__global__ void combine_kernel(const int* __restrict__ subj,
                               const int* __restrict__ rel,
                               const float* __restrict__ emb,
                               const float* __restrict__ rels,
                               short* __restrict__ out) {
    const int b = blockIdx.x;
    const int t = threadIdx.x;
    const float v = emb[(size_t)subj[b] * EMBD + t] * rels[rel[b] * EMBD + t];
    out[b * EMBD + t] = f2bf(v);
}

// One block's work: W-col strip x all 1024 batch rows (r5 structure).
template <int W>
__device__ __forceinline__ void block_body(const short* __restrict__ A,
                                           const float* __restrict__ B,
                                           float* __restrict__ C,
                                           short* Bs, int n0, int tid) {
    constexpr int NI = W / 16;            // MFMA col-tiles (13 or 12)

    // ---- stage B strip: W*128 bf16, W/2 elems/thread (NI chunks of 8)
#pragma unroll
    for (int c = 0; c < NI; ++c) {
        const int e = (c * 256 + tid) * 8;
        const int rr = e >> 7;
        const int k  = e & 127;
        const float* p = B + (size_t)(n0 + rr) * EMBD + k;
        f32x4_t lo = *reinterpret_cast<const f32x4_t*>(p);
        f32x4_t hi = *reinterpret_cast<const f32x4_t*>(p + 4);
        bf16x8_t v;
#pragma unroll
        for (int j = 0; j < 4; ++j) { v[j] = f2bf(lo[j]); v[4 + j] = f2bf(hi[j]); }
        const int byteaddr = rr * 256 + ((k * 2) ^ ((rr & 7) << 4));
        *reinterpret_cast<bf16x8_t*>(reinterpret_cast<char*>(Bs) + byteaddr) = v;
    }
    __syncthreads();

    const int w  = tid >> 6;
    const int l  = tid & 63;
    const int fr = l & 15;
    const int fq = l >> 4;
    const int swz = (fr & 7) << 4;
    const char* BsBase = reinterpret_cast<const char*>(Bs) + fr * 256;

#pragma unroll
    for (int p = 0; p < NPASS; ++p) {
        const int m0 = p * 128 + w * 32;
        bf16x8_t a[2][4];
#pragma unroll
        for (int mi = 0; mi < 2; ++mi) {
            const short* qp = A + (m0 + mi * 16 + fr) * EMBD + fq * 8;
#pragma unroll
            for (int kk = 0; kk < 4; ++kk)
                a[mi][kk] = *reinterpret_cast<const bf16x8_t*>(qp + kk * 32);
        }

        f32x4_t acc[2][NI] = {};
#pragma unroll
        for (int kk = 0; kk < 4; ++kk) {
#pragma unroll
            for (int base = 0; base < NI; base += 5) {
                constexpr int REM = 0;  (void)REM;
                bf16x8_t bfr[5];
#pragma unroll
                for (int j = 0; j < 5; ++j) {
                    if (base + j < NI) {
                        const int ni = base + j;
                        const int byteoff = ni * 4096 + ((kk * 64 + fq * 16) ^ swz);
                        bfr[j] = *reinterpret_cast<const bf16x8_t*>(BsBase + byteoff);
                    }
                }
#pragma unroll
                for (int mi = 0; mi < 2; ++mi)
#pragma unroll
                    for (int j = 0; j < 5; ++j)
                        if (base + j < NI)
                            acc[mi][base + j] = __builtin_amdgcn_mfma_f32_16x16x32_bf16(
                                bfr[j], a[mi][kk], acc[mi][base + j], 0, 0, 0);
            }
        }

#pragma unroll
        for (int mi = 0; mi < 2; ++mi) {
            const size_t rowoff = (size_t)(m0 + mi * 16 + fr) * NODES;
#pragma unroll
            for (int ni = 0; ni < NI; ++ni)
                *reinterpret_cast<f32x4_t*>(C + rowoff + n0 + ni * 16 + fq * 4) =
                    acc[mi][ni];
        }
    }
}

// Grid = 512 blocks (2/CU exactly). Strip widths 208 (106 blocks) / 192 (406),
// wide strips spread evenly by n0(bid) = 192*bid + 16*floor(bid*106/512).
__global__ __launch_bounds__(256, 2) void distmult_kernel(
        const short* __restrict__ A,
        const float* __restrict__ B,
        float* __restrict__ C) {
    extern __shared__ short Bs[];          // up to 208*128 bf16 = 52 KB
    const int bid = (int)blockIdx.x;
    const int n0 = strip_start(bid);
    const int wdt = strip_start(bid + 1) - n0;   // 192 or 208, block-uniform
    const int tid = (int)threadIdx.x;
    if (wdt == 208) block_body<208>(A, B, C, Bs, n0, tid);
    else            block_body<192>(A, B, C, Bs, n0, tid);
}

extern "C" void kernel_launch(void* const* d_in, const int* in_sizes, int n_in,
                              void* d_out, int out_size, void* d_ws, size_t ws_size,
                              hipStream_t stream) {
    const int*   subj = (const int*)d_in[0];
    const int*   rel  = (const int*)d_in[1];
    const float* emb  = (const float*)d_in[2];
    const float* rels = (const float*)d_in[3];
    float* out = (float*)d_out;
    short* combined = (short*)d_ws;   // 256 KB

    combine_kernel<<<BATCH, EMBD, 0, stream>>>(subj, rel, emb, rels, combined);
    distmult_kernel<<<NBLK, 256, 208 * EMBD * sizeof(short), stream>>>(
        combined, emb, out);
}